// Round 5
// baseline (284.619 us; speedup 1.0000x reference)
//
#include <hip/hip_runtime.h>
#include <math.h>

#define T_TOKENS 16384
#define HDIM     2048
#define NEXP     128
#define TOPK     8

#define BK    64                 // k per chunk (2 MFMA k-steps)
#define NCH   (HDIM / BK)        // 32 chunks
#define TM    32                 // tokens per block

#define F16_MIN_NORM    6.1035156e-05f
#define SPLIT_SCALE     4096.0f
#define INV_SPLIT_SCALE 2.44140625e-04f   // 2^-12

typedef __attribute__((ext_vector_type(8))) _Float16 f16x8;  // A/B frag: 4 VGPR
typedef __attribute__((ext_vector_type(4))) float    f32x4;  // C/D frag + loads

// x = hi + lo*2^-12 (f16 RNE each); residual <= 2^-24|x|. Numerics verified R3-R8.
__device__ __forceinline__ void f16split(float f, _Float16& hi, _Float16& lo) {
    _Float16 h = (_Float16)f;
    float back = (float)h;
    if (fabsf(f) < F16_MIN_NORM) { h = (_Float16)0.f; back = 0.f; }
    lo = (_Float16)((f - back) * SPLIT_SCALE);
    hi = h;
}

// ---- prep: split w AND repack into MFMA B-frag order (verified R5-R8, unchanged) ----
// packed[s]: ((kk*8 + nt)*64 + lane) * 8 f16; kk = global 32-k step, nt = expert/16.
__global__ __launch_bounds__(256) void pack_w(const float* __restrict__ w,
                                              unsigned short* __restrict__ wp1,
                                              unsigned short* __restrict__ wp2) {
    int p = blockIdx.x * 256 + threadIdx.x;       // 0 .. 64*8*64-1
    int lane = p & 63, nt = (p >> 6) & 7, kk = p >> 9;
    int col = lane & 15, quad = lane >> 4;
    const float* src = w + (size_t)(nt * 16 + col) * HDIM + kk * 32 + quad * 8;
    unsigned short h[8], l[8];
#pragma unroll
    for (int j = 0; j < 8; ++j) {
        _Float16 hh, ll;
        f16split(src[j], hh, ll);
        union { _Float16 x; unsigned short u; } ch, cl;
        ch.x = hh; cl.x = ll;
        h[j] = ch.u; l[j] = cl.u;
    }
    *(uint4*)(wp1 + (size_t)p * 8) = *(const uint4*)h;
    *(uint4*)(wp2 + (size_t)p * 8) = *(const uint4*)l;
}

struct ARegs { f32x4 v[8]; };    // [m(2)][kk(2)][half(2)] — static indexing only
struct BRegs { f16x8 v[8]; };    // [(kk*2+j)*2+plane]     — static indexing only

// ---- fused gate v6: distance-1 ping-pong, issue-early/consume-late, barrier-free ----
// R4 failed because consume-at-distance-2 kept 4 buffer sets live -> compiler aliased
// them (VGPR=120 < 128 needed) and sank loads to uses. v6: distance-1 — at any point
// exactly one set per operand is live-with-data and one is MID-FLIGHT (outstanding
// loads writing it; compiler cannot alias that). Within an iteration: issue next-chunk
// A(HBM ~900cy) + B(L2 ~250cy) FIRST, then ~400cy of split VALU, then MFMA. vmcnt
// FIFO steady-states at 24/16 outstanding; compiler emits counted waits; no barrier,
// no LDS in the main loop. Waves free-run (2 blocks/CU x 4 waves).
__global__ __launch_bounds__(256, 2) void moe_gate(const float* __restrict__ x,
                                                   const unsigned short* __restrict__ wp1,
                                                   const unsigned short* __restrict__ wp2,
                                                   float* __restrict__ out_idx,
                                                   float* __restrict__ out_w) {
    __shared__ __align__(16) float epil[TM * 132];   // [32][132] f32 = 16.9 KB

    const int tid  = threadIdx.x;
    const int lane = tid & 63;
    const int wv   = tid >> 6;        // expert group 0..3
    const int col  = lane & 15;       // A: token-in-tile, B: expert-in-tile, D: col
    const int quad = lane >> 4;       // A/B: k-seg, D: row group
    const long tok0 = (long)blockIdx.x * TM;

    // lane reads x[token = m*16+col][k = ch*64 + kk*32 + quad*8 .. +8]
    const float* xg = x + (tok0 + col) * (long)HDIM + quad * 8;

    f32x4 acc[2][2], accc[2][2];      // [m][j] main + cross (static-indexed)
#pragma unroll
    for (int m = 0; m < 2; ++m)
#pragma unroll
        for (int j = 0; j < 2; ++j) { acc[m][j] = (f32x4){0,0,0,0}; accc[m][j] = (f32x4){0,0,0,0}; }

    f16x8 af1[2][2], af2[2][2];       // [kk][m] hi/lo planes (transient per chunk)

    auto loadA = [&](int ch, ARegs& A) {    // 8 coalesced 16 B loads (16 rows x 128 B)
#pragma unroll
        for (int m = 0; m < 2; ++m) {
            const float* p = xg + (size_t)m * 16 * HDIM + ch * BK;
            A.v[m * 4 + 0] = *(const f32x4*)(p);
            A.v[m * 4 + 1] = *(const f32x4*)(p + 4);
            A.v[m * 4 + 2] = *(const f32x4*)(p + 32);
            A.v[m * 4 + 3] = *(const f32x4*)(p + 36);
        }
    };
    auto loadB = [&](int ch, BRegs& B) {    // 8 lane-contiguous 16 B loads (1 KB/instr, L2)
        const size_t cho = (size_t)ch * 8192;
#pragma unroll
        for (int kk = 0; kk < 2; ++kk)
#pragma unroll
            for (int j = 0; j < 2; ++j) {
                const size_t o = cho + (size_t)(((kk * 8) + (wv * 2 + j)) * 64 + lane) * 8;
                B.v[(kk * 2 + j) * 2 + 0] = *(const f16x8*)(wp1 + o);
                B.v[(kk * 2 + j) * 2 + 1] = *(const f16x8*)(wp2 + o);
            }
    };
    auto splitA = [&](ARegs& A) {           // Av -> af planes (32 f16splits, ~400 cyc VALU)
#pragma unroll
        for (int m = 0; m < 2; ++m)
#pragma unroll
            for (int kk = 0; kk < 2; ++kk) {
                f32x4 v0 = A.v[m * 4 + kk * 2 + 0];
                f32x4 v1 = A.v[m * 4 + kk * 2 + 1];
#pragma unroll
                for (int j = 0; j < 8; ++j) {
                    float f = (j < 4) ? v0[j] : v1[j - 4];
                    _Float16 hh, ll;
                    f16split(f, hh, ll);
                    af1[kk][m][j] = hh;
                    af2[kk][m][j] = ll;
                }
            }
    };
    auto mfmaStep = [&](BRegs& B) {
#pragma unroll
        for (int kk = 0; kk < 2; ++kk)
#pragma unroll
            for (int j = 0; j < 2; ++j) {
                f16x8 bf1 = B.v[(kk * 2 + j) * 2 + 0];
                f16x8 bf2 = B.v[(kk * 2 + j) * 2 + 1];
#pragma unroll
                for (int m = 0; m < 2; ++m) {
                    acc[m][j]  = __builtin_amdgcn_mfma_f32_16x16x32_f16(af1[kk][m], bf1, acc[m][j],  0, 0, 0);
                    accc[m][j] = __builtin_amdgcn_mfma_f32_16x16x32_f16(af1[kk][m], bf2, accc[m][j], 0, 0, 0);
                    accc[m][j] = __builtin_amdgcn_mfma_f32_16x16x32_f16(af2[kk][m], bf1, accc[m][j], 0, 0, 0);
                }
            }
    };

    ARegs A0, A1;                     // distance-1 ping-pong
    BRegs B0, B1;

    loadA(0, A0); loadB(0, B0);       // chunk 0 in flight

    for (int ch = 0; ch < NCH; ch += 2) {
        // even half: set1 <- ch+1 (issue), consume set0 = ch
        if (ch + 1 < NCH) { loadA(ch + 1, A1); loadB(ch + 1, B1); }
        splitA(A0);                   // counted wait: A(ch) only (oldest in FIFO)
        mfmaStep(B0);                 // counted wait: B(ch); covered by split VALU
        // odd half: set0 <- ch+2 (issue), consume set1 = ch+1
        if (ch + 2 < NCH) { loadA(ch + 2, A0); loadB(ch + 2, B0); }
        if (ch + 1 < NCH) { splitA(A1); mfmaStep(B1); }
    }

    // ---- epilogue: logits -> LDS; D layout: token = m*16+quad*4+r, expert = (wv*2+j)*16+col
#pragma unroll
    for (int m = 0; m < 2; ++m)
#pragma unroll
        for (int j = 0; j < 2; ++j)
#pragma unroll
            for (int r = 0; r < 4; ++r)
                epil[(m * 16 + quad * 4 + r) * 132 + (wv * 2 + j) * 16 + col] =
                    acc[m][j][r] + accc[m][j][r] * INV_SPLIT_SCALE;
    __syncthreads();

    // ---- top-8 + renorm softmax: 8 tokens per wave (butterfly verified R1-R8) ----
    for (int i = 0; i < 8; ++i) {
        const int t = wv * 8 + i;
        float2 p = *(const float2*)(epil + t * 132 + 2 * lane);
        float v0 = p.x, v1 = p.y;
        const int i0 = 2 * lane, i1 = 2 * lane + 1;

        float topv[TOPK];
        int topi[TOPK];
#pragma unroll
        for (int s = 0; s < TOPK; ++s) {
            float mv = (v0 >= v1) ? v0 : v1;          // tie -> smaller index
            int   mi = (v0 >= v1) ? i0 : i1;
#pragma unroll
            for (int off = 32; off >= 1; off >>= 1) {
                float ov = __shfl_xor(mv, off);
                int   oi = __shfl_xor(mi, off);
                if (ov > mv || (ov == mv && oi < mi)) { mv = ov; mi = oi; }
            }
            topv[s] = mv; topi[s] = mi;
            if (i0 == mi) v0 = -INFINITY;
            if (i1 == mi) v1 = -INFINITY;
        }

        const float m = topv[0];
        float sum = 0.f;
#pragma unroll
        for (int s = 0; s < TOPK; ++s) sum += expf(topv[s] - m);
        const float inv = 1.f / sum;

        float myv = topv[0]; int myi = topi[0];
#pragma unroll
        for (int s = 1; s < TOPK; ++s)
            if (lane == s) { myv = topv[s]; myi = topi[s]; }

        if (lane < TOPK) {
            long tok = tok0 + t;
            out_idx[tok * TOPK + lane] = (float)myi;
            out_w[tok * TOPK + lane]   = expf(myv - m) * inv;
        }
    }
}

extern "C" void kernel_launch(void* const* d_in, const int* in_sizes, int n_in,
                              void* d_out, int out_size, void* d_ws, size_t ws_size,
                              hipStream_t stream) {
    const float* x = (const float*)d_in[0];   // [4,4096,2048] fp32
    const float* w = (const float*)d_in[1];   // [128,2048] fp32
    float* out = (float*)d_out;               // [T*8 idx][T*8 weights] flat fp32

    unsigned short* wp1 = (unsigned short*)d_ws;           // 512 KB packed hi
    unsigned short* wp2 = wp1 + (size_t)NEXP * HDIM;       // 512 KB packed lo

    pack_w<<<(64 * 8 * 64) / 256, 256, 0, stream>>>(w, wp1, wp2);
    moe_gate<<<T_TOKENS / TM, 256, 0, stream>>>(x, wp1, wp2, out, out + (size_t)T_TOKENS * TOPK);
}

// Round 6
// 279.533 us; speedup vs baseline: 1.0182x; 1.0182x over previous
//
#include <hip/hip_runtime.h>
#include <math.h>

#define T_TOKENS 16384
#define HDIM     2048
#define NEXP     128
#define TOPK     8

#define BK    64                 // k per chunk (2 MFMA k-steps)
#define NCH   (HDIM / BK)        // 32 chunks
#define TM    32                 // tokens per block

#define F16_MIN_NORM    6.1035156e-05f
#define SPLIT_SCALE     4096.0f
#define INV_SPLIT_SCALE 2.44140625e-04f   // 2^-12

typedef __attribute__((ext_vector_type(8))) _Float16 f16x8;  // A/B frag: 4 VGPR
typedef __attribute__((ext_vector_type(4))) float    f32x4;  // C/D frag + loads

// Inline-asm load: SGPR base + 32-bit per-lane voffset + 13-bit imm. asm volatile
// chain = program-order issue; compiler cannot sink/alias/auto-wait these.
#define GLOAD4(dst, base, voff, imm) \
    asm volatile("global_load_dwordx4 %0, %1, %2 offset:" imm \
                 : "=v"(dst) : "v"(voff), "s"(base) : "memory")
#define VMWAIT(n) asm volatile("s_waitcnt vmcnt(" #n ")" ::: "memory")
#define SB0() __builtin_amdgcn_sched_barrier(0)

// x = hi + lo*2^-12 (f16 RNE each); residual <= 2^-24|x|. Numerics verified R3-R8.
__device__ __forceinline__ void f16split(float f, _Float16& hi, _Float16& lo) {
    _Float16 h = (_Float16)f;
    float back = (float)h;
    if (fabsf(f) < F16_MIN_NORM) { h = (_Float16)0.f; back = 0.f; }
    lo = (_Float16)((f - back) * SPLIT_SCALE);
    hi = h;
}

// ---- prep: split w AND repack into MFMA B-frag order (verified R5-R8, unchanged) ----
// packed[s]: ((kk*8 + nt)*64 + lane) * 8 f16; kk = global 32-k step, nt = expert/16.
__global__ __launch_bounds__(256) void pack_w(const float* __restrict__ w,
                                              unsigned short* __restrict__ wp1,
                                              unsigned short* __restrict__ wp2) {
    int p = blockIdx.x * 256 + threadIdx.x;       // 0 .. 64*8*64-1
    int lane = p & 63, nt = (p >> 6) & 7, kk = p >> 9;
    int col = lane & 15, quad = lane >> 4;
    const float* src = w + (size_t)(nt * 16 + col) * HDIM + kk * 32 + quad * 8;
    unsigned short h[8], l[8];
#pragma unroll
    for (int j = 0; j < 8; ++j) {
        _Float16 hh, ll;
        f16split(src[j], hh, ll);
        union { _Float16 x; unsigned short u; } ch, cl;
        ch.x = hh; cl.x = ll;
        h[j] = ch.u; l[j] = cl.u;
    }
    *(uint4*)(wp1 + (size_t)p * 8) = *(const uint4*)h;
    *(uint4*)(wp2 + (size_t)p * 8) = *(const uint4*)l;
}

struct ARegs { f32x4 v[8]; };    // [m(2)]{+0,+16,+128,+144}B — static indexing only
struct BRegs { f16x8 v[8]; };    // [(kk*2+j)*2+plane]        — static indexing only

// ---- fused gate v7: inline-asm load pipeline, hand-counted vmcnt, barrier-free ----
// R1-R5 all failed identically: hipcc collapses ANY source-level pipeline (sinks
// loads to uses; R5 VGPR=100 < 192 needed proves sets were aliased). v7 makes the
// pipeline opaque to the compiler: every main-loop load is asm volatile
// global_load_dwordx4 (program-order issue, no auto-waits, regs pinned by "=v"),
// waits are hand-counted s_waitcnt vmcnt(16) (steady state: drain chunk ch, leave
// ch+1's 16 in flight; vmcnt(0) only at the tail), sched_barrier(0) fences consumer
// hoisting (rule #18). Chunk loop fully unrolled -> straight-line, no phi copies of
// in-flight regs. No barriers, no main-loop LDS: 8 waves/CU free-run.
__global__ __launch_bounds__(256, 2) void moe_gate(const float* __restrict__ x,
                                                   const unsigned short* __restrict__ wp1,
                                                   const unsigned short* __restrict__ wp2,
                                                   float* __restrict__ out_idx,
                                                   float* __restrict__ out_w) {
    __shared__ __align__(16) float epil[TM * 132];   // [32][132] f32 = 16.9 KB

    const int tid  = threadIdx.x;
    const int lane = tid & 63;
    const int wv   = tid >> 6;        // expert group 0..3
    const int col  = lane & 15;       // A: token-in-tile, B: expert-in-tile, D: col
    const int quad = lane >> 4;       // A/B: k-seg, D: row group
    const long tok0 = (long)blockIdx.x * TM;

    // SGPR bases (block-uniform); per-lane 32-bit byte voffsets.
    const float* xbase = x + tok0 * HDIM;            // A base; lane reads rows tok0+m*16+col
    const unsigned voffA0 = (unsigned)(col * (HDIM * 4) + quad * 32);          // m=0
    const unsigned voffA1 = voffA0 + 16u * (HDIM * 4);                         // m=1
    const unsigned voffB  = (unsigned)(wv * 2048 + lane * 16);                 // nt-base=2wv

    f32x4 acc[2][2], accc[2][2];      // [m][j] main + cross (static-indexed)
#pragma unroll
    for (int m = 0; m < 2; ++m)
#pragma unroll
        for (int j = 0; j < 2; ++j) { acc[m][j] = (f32x4){0,0,0,0}; accc[m][j] = (f32x4){0,0,0,0}; }

    f16x8 af1[2][2], af2[2][2];       // [kk][m] hi/lo planes (transient per chunk)

    // issue: 8 asm loads, 2 voffset regs, imm-folded sub-offsets. Byte layout per
    // chunk/row: {0,16,128,144} relative to quad*32 (matches verified R0-R5 loads).
    auto issueA = [&](int ch, ARegs& A) {
        const unsigned v0 = voffA0 + (unsigned)ch * 256u;
        const unsigned v1 = voffA1 + (unsigned)ch * 256u;
        GLOAD4(A.v[0], xbase, v0, "0");
        GLOAD4(A.v[1], xbase, v0, "16");
        GLOAD4(A.v[2], xbase, v0, "128");
        GLOAD4(A.v[3], xbase, v0, "144");
        GLOAD4(A.v[4], xbase, v1, "0");
        GLOAD4(A.v[5], xbase, v1, "16");
        GLOAD4(A.v[6], xbase, v1, "128");
        GLOAD4(A.v[7], xbase, v1, "144");
    };
    // B bytes: ch*16384 + kk*8192 + wv*2048 + j*1024 + lane*16 (verified layout).
    auto issueB = [&](int ch, BRegs& B) {
        const unsigned vb  = voffB + (unsigned)ch * 16384u;
        const unsigned vb2 = vb + 8192u;
        GLOAD4(B.v[0], wp1, vb,  "0");      // kk0 j0 hi
        GLOAD4(B.v[1], wp2, vb,  "0");      // kk0 j0 lo
        GLOAD4(B.v[2], wp1, vb,  "1024");   // kk0 j1 hi
        GLOAD4(B.v[3], wp2, vb,  "1024");
        GLOAD4(B.v[4], wp1, vb2, "0");      // kk1 j0
        GLOAD4(B.v[5], wp2, vb2, "0");
        GLOAD4(B.v[6], wp1, vb2, "1024");   // kk1 j1
        GLOAD4(B.v[7], wp2, vb2, "1024");
    };
    auto splitA = [&](ARegs& A) {           // Av -> af planes (32 f16splits)
#pragma unroll
        for (int m = 0; m < 2; ++m)
#pragma unroll
            for (int kk = 0; kk < 2; ++kk) {
                f32x4 v0 = A.v[m * 4 + kk * 2 + 0];
                f32x4 v1 = A.v[m * 4 + kk * 2 + 1];
#pragma unroll
                for (int j = 0; j < 8; ++j) {
                    float f = (j < 4) ? v0[j] : v1[j - 4];
                    _Float16 hh, ll;
                    f16split(f, hh, ll);
                    af1[kk][m][j] = hh;
                    af2[kk][m][j] = ll;
                }
            }
    };
    auto mfmaStep = [&](BRegs& B) {
#pragma unroll
        for (int kk = 0; kk < 2; ++kk)
#pragma unroll
            for (int j = 0; j < 2; ++j) {
                f16x8 bf1 = B.v[(kk * 2 + j) * 2 + 0];
                f16x8 bf2 = B.v[(kk * 2 + j) * 2 + 1];
#pragma unroll
                for (int m = 0; m < 2; ++m) {
                    acc[m][j]  = __builtin_amdgcn_mfma_f32_16x16x32_f16(af1[kk][m], bf1, acc[m][j],  0, 0, 0);
                    accc[m][j] = __builtin_amdgcn_mfma_f32_16x16x32_f16(af1[kk][m], bf2, accc[m][j], 0, 0, 0);
                    accc[m][j] = __builtin_amdgcn_mfma_f32_16x16x32_f16(af2[kk][m], bf1, accc[m][j], 0, 0, 0);
                }
            }
    };

    ARegs A0, A1;                     // distance-1 ping-pong, asm-pinned registers
    BRegs B0, B1;

    // FIFO ledger (per wave; loop has NO other vmem): steady state 32 outstanding
    // after issue, vmcnt(16) drains exactly the chunk being consumed.
    issueA(0, A0); issueB(0, B0);                    // out: 16

#pragma unroll
    for (int cp = 0; cp < NCH / 2; ++cp) {
        const int ch = cp * 2;
        // even half: issue ch+1, wait ch, consume set0
        issueA(ch + 1, A1); issueB(ch + 1, B1);      // out: 32
        VMWAIT(16); SB0();                           // drain A(ch)+B(ch); leave ch+1
        splitA(A0); mfmaStep(B0);
        // odd half: issue ch+2 (except tail), wait ch+1, consume set1
        if (ch + 2 < NCH) {
            issueA(ch + 2, A0); issueB(ch + 2, B0);  // out: 32
            VMWAIT(16); SB0();                       // drain A(ch+1)+B(ch+1)
        } else {
            VMWAIT(0); SB0();                        // tail: drain last chunk
        }
        splitA(A1); mfmaStep(B1);
    }

    // ---- epilogue: logits -> LDS; D layout: token = m*16+quad*4+r, expert = (wv*2+j)*16+col
#pragma unroll
    for (int m = 0; m < 2; ++m)
#pragma unroll
        for (int j = 0; j < 2; ++j)
#pragma unroll
            for (int r = 0; r < 4; ++r)
                epil[(m * 16 + quad * 4 + r) * 132 + (wv * 2 + j) * 16 + col] =
                    acc[m][j][r] + accc[m][j][r] * INV_SPLIT_SCALE;
    __syncthreads();

    // ---- top-8 + renorm softmax: 8 tokens per wave (butterfly verified R1-R8) ----
    for (int i = 0; i < 8; ++i) {
        const int t = wv * 8 + i;
        float2 p = *(const float2*)(epil + t * 132 + 2 * lane);
        float v0 = p.x, v1 = p.y;
        const int i0 = 2 * lane, i1 = 2 * lane + 1;

        float topv[TOPK];
        int topi[TOPK];
#pragma unroll
        for (int s = 0; s < TOPK; ++s) {
            float mv = (v0 >= v1) ? v0 : v1;          // tie -> smaller index
            int   mi = (v0 >= v1) ? i0 : i1;
#pragma unroll
            for (int off = 32; off >= 1; off >>= 1) {
                float ov = __shfl_xor(mv, off);
                int   oi = __shfl_xor(mi, off);
                if (ov > mv || (ov == mv && oi < mi)) { mv = ov; mi = oi; }
            }
            topv[s] = mv; topi[s] = mi;
            if (i0 == mi) v0 = -INFINITY;
            if (i1 == mi) v1 = -INFINITY;
        }

        const float m = topv[0];
        float sum = 0.f;
#pragma unroll
        for (int s = 0; s < TOPK; ++s) sum += expf(topv[s] - m);
        const float inv = 1.f / sum;

        float myv = topv[0]; int myi = topi[0];
#pragma unroll
        for (int s = 1; s < TOPK; ++s)
            if (lane == s) { myv = topv[s]; myi = topi[s]; }

        if (lane < TOPK) {
            long tok = tok0 + t;
            out_idx[tok * TOPK + lane] = (float)myi;
            out_w[tok * TOPK + lane]   = expf(myv - m) * inv;
        }
    }
}

extern "C" void kernel_launch(void* const* d_in, const int* in_sizes, int n_in,
                              void* d_out, int out_size, void* d_ws, size_t ws_size,
                              hipStream_t stream) {
    const float* x = (const float*)d_in[0];   // [4,4096,2048] fp32
    const float* w = (const float*)d_in[1];   // [128,2048] fp32
    float* out = (float*)d_out;               // [T*8 idx][T*8 weights] flat fp32

    unsigned short* wp1 = (unsigned short*)d_ws;           // 512 KB packed hi
    unsigned short* wp2 = wp1 + (size_t)NEXP * HDIM;       // 512 KB packed lo

    pack_w<<<(64 * 8 * 64) / 256, 256, 0, stream>>>(w, wp1, wp2);
    moe_gate<<<T_TOKENS / TM, 256, 0, stream>>>(x, wp1, wp2, out, out + (size_t)T_TOKENS * TOPK);
}

// Round 7
// 243.552 us; speedup vs baseline: 1.1686x; 1.1477x over previous
//
#include <hip/hip_runtime.h>
#include <math.h>

#define T_TOKENS 16384
#define HDIM     2048
#define NEXP     128
#define TOPK     8

#define BK    64                 // k per chunk (2 MFMA k-steps)
#define NCH   (HDIM / BK)        // 32 chunks
#define TM    64                 // tokens per block

#define F16_MIN_NORM    6.1035156e-05f
#define SPLIT_SCALE     4096.0f
#define INV_SPLIT_SCALE 2.44140625e-04f   // 2^-12

typedef __attribute__((ext_vector_type(8))) _Float16 f16x8;  // A/B frag: 4 VGPR
typedef __attribute__((ext_vector_type(4))) float    f32x4;  // C/D frag + loads

#define VMWAIT(n) asm volatile("s_waitcnt vmcnt(" #n ")" ::: "memory")
#define LGKM0()   asm volatile("s_waitcnt lgkmcnt(0)" ::: "memory")
#define SB0()     __builtin_amdgcn_sched_barrier(0)

// x = hi + lo*2^-12 (f16 RNE each); residual <= 2^-24|x|. Numerics verified R3-R8.
__device__ __forceinline__ void f16split(float f, _Float16& hi, _Float16& lo) {
    _Float16 h = (_Float16)f;
    float back = (float)h;
    if (fabsf(f) < F16_MIN_NORM) { h = (_Float16)0.f; back = 0.f; }
    lo = (_Float16)((f - back) * SPLIT_SCALE);
    hi = h;
}

// ---- prep: split w AND repack into MFMA B-frag order (verified, unchanged) ----
// packed[s]: ((kk*8 + nt)*64 + lane) * 8 f16; kk = global 32-k step, nt = expert/16.
__global__ __launch_bounds__(256) void pack_w(const float* __restrict__ w,
                                              unsigned short* __restrict__ wp1,
                                              unsigned short* __restrict__ wp2) {
    int p = blockIdx.x * 256 + threadIdx.x;       // 0 .. 64*8*64-1
    int lane = p & 63, nt = (p >> 6) & 7, kk = p >> 9;
    int col = lane & 15, quad = lane >> 4;
    const float* src = w + (size_t)(nt * 16 + col) * HDIM + kk * 32 + quad * 8;
    unsigned short h[8], l[8];
#pragma unroll
    for (int j = 0; j < 8; ++j) {
        _Float16 hh, ll;
        f16split(src[j], hh, ll);
        union { _Float16 x; unsigned short u; } ch, cl;
        ch.x = hh; cl.x = ll;
        h[j] = ch.u; l[j] = cl.u;
    }
    *(uint4*)(wp1 + (size_t)p * 8) = *(const uint4*)h;
    *(uint4*)(wp2 + (size_t)p * 8) = *(const uint4*)l;
}

// ---- fused gate v8: R0 structure scaled to TM=64 + m201-style overlap ----
// Theory (R6 post-mortem): the invariant 140-150us across R2-R6 is per-CU memory
// REQUEST count (divergent per-wave A gathers x4 duplication + per-wave B), not
// latency. v8 minimizes requests/token: cooperative coalesced A staging (each
// thread one 32B row-chunk; 256 lines/chunk/block, frag-order LDS, split shared
// by all 8 waves) + B via global_load_lds (512 lines/chunk/block serving 64
// tokens). Double-buffered LDS (2 x {A 16KB + B 32KB} = 96KB dynamic, 1 block/CU,
// 512 thr). Overlap per m201's proven pattern: stage chunk ch+1 into the buffer
// whose reads completed before the PREVIOUS barrier; raw s_barrier; hand-counted
// VMWAIT(2) (never 0 until tail). Ledger per iter (per thread, in order):
//   entry FIFO=[A(ch+1):2]
//   S0 stage DMA(ch+1)->buf[q].B (+4)            FIFO=[A:2, DMA:4]
//   S1 splitWriteA->buf[q].A  (compiler waits A(ch+1) regs = vmcnt(4))
//   S2 loadA(ch+2) (+2)                          FIFO=[DMA:4, A':2]
//   S3 ds_read frags buf[p] + 24 MFMA
//   S5 VMWAIT(2)  -> drains DMA(ch+1) exactly, leaves A(ch+2)
//   S6 LGKM0 + s_barrier  -> buf[q] published    exit FIFO=[A':2]
__global__ __launch_bounds__(512, 2) void moe_gate(const float* __restrict__ x,
                                                   const unsigned short* __restrict__ wp1,
                                                   const unsigned short* __restrict__ wp2,
                                                   float* __restrict__ out_idx,
                                                   float* __restrict__ out_w) {
    // per-buf u16 layout: A1[0,4096) A2[4096,8192) B1[8192,16384) B2[16384,24576)
    extern __shared__ __align__(16) unsigned char smem[];      // 2 x 49152 B
    float* epil = (float*)smem;                                // [64][132] f32 = 33.8 KB union

    const int tid  = threadIdx.x;
    const int lane = tid & 63;
    const int wv   = tid >> 6;        // 0..7
    const int mg   = wv >> 2;         // token half: m-tiles {2mg, 2mg+1}
    const int ng   = wv & 3;          // expert group: nt = {2ng, 2ng+1}
    const int col  = lane & 15;       // A: token-in-tile, B: expert-in-tile, D: col
    const int quad = lane >> 4;       // A/B: k-seg, D: row group
    const long tok0 = (long)blockIdx.x * TM;

    // A staging: thread t -> row srow = t>>3 (0..63), kseg = t&7 -> 8 f32 at k=kseg*8.
    // 8 threads cover one 256B row-chunk (fully coalesced). All 8 elems map to ONE
    // (kk,quad) frag cell -> single uint4 store per plane in frag order (R0-verified).
    const int srow = tid >> 3, skseg = tid & 7;
    const float* xgs = x + (tok0 + srow) * (long)HDIM + skseg * 8;
    const int adst = (((skseg >> 2) * 4 + (srow >> 4)) * 64 + (skseg & 3) * 16 + (srow & 15)) * 8;

    f32x4 acc[2][2], accc[2][2];      // [m][j] main + cross (static-indexed)
#pragma unroll
    for (int m = 0; m < 2; ++m)
#pragma unroll
        for (int j = 0; j < 2; ++j) { acc[m][j] = (f32x4){0,0,0,0}; accc[m][j] = (f32x4){0,0,0,0}; }

    f32x4 Av0, Av1;                   // this thread's 8 staged f32 (1-deep prefetch)

    auto bufp = [&](int b) -> unsigned short* { return (unsigned short*)(smem + b * 49152); };

    auto loadA = [&](int ch) {        // 2 coalesced 16B loads
        Av0 = *(const f32x4*)(xgs + ch * BK);
        Av1 = *(const f32x4*)(xgs + ch * BK + 4);
    };
    auto splitWriteA = [&](int b) {   // 8 f16splits -> one uint4 per plane, frag order
        unsigned short h[8], l[8];
#pragma unroll
        for (int j = 0; j < 8; ++j) {
            _Float16 hh, ll;
            f16split(j < 4 ? Av0[j] : Av1[j - 4], hh, ll);
            union { _Float16 x; unsigned short u; } ch_, cl_;
            ch_.x = hh; cl_.x = ll;
            h[j] = ch_.u; l[j] = cl_.u;
        }
        *(uint4*)(bufp(b) + adst)        = *(const uint4*)h;
        *(uint4*)(bufp(b) + 4096 + adst) = *(const uint4*)l;
    };
    auto stageB = [&](int ch, int b) {     // 4 gload_lds x 16B; dst = uniform + lane*16
        const unsigned short* s1 = wp1 + (size_t)ch * 8192;
        const unsigned short* s2 = wp2 + (size_t)ch * 8192;
        unsigned short* d1 = bufp(b) + 8192;
        unsigned short* d2 = bufp(b) + 16384;
#pragma unroll
        for (int i = 0; i < 2; ++i) {
            const int off = (i * 512 + tid) * 8;
            __builtin_amdgcn_global_load_lds((const __attribute__((address_space(1))) void*)(s1 + off),
                                             (__attribute__((address_space(3))) void*)(d1 + off), 16, 0, 0);
            __builtin_amdgcn_global_load_lds((const __attribute__((address_space(1))) void*)(s2 + off),
                                             (__attribute__((address_space(3))) void*)(d2 + off), 16, 0, 0);
        }
    };
    auto mfmaStep = [&](int b) {      // 16 lane-contiguous ds_read_b128 (conflict-free) + 24 MFMA
        const unsigned short* a1 = bufp(b);
        const unsigned short* a2 = a1 + 4096;
        const unsigned short* b1 = a1 + 8192;
        const unsigned short* b2 = a1 + 16384;
#pragma unroll
        for (int kk = 0; kk < 2; ++kk) {
            f16x8 af1[2], af2[2];
#pragma unroll
            for (int m = 0; m < 2; ++m) {
                const int ao = ((kk * 4 + (mg * 2 + m)) * 64 + lane) * 8;
                af1[m] = *(const f16x8*)(a1 + ao);
                af2[m] = *(const f16x8*)(a2 + ao);
            }
#pragma unroll
            for (int j = 0; j < 2; ++j) {
                const int nt = ng * 2 + j;
                const int bo = ((kk * 8 + nt) * 64 + lane) * 8;
                f16x8 bf1 = *(const f16x8*)(b1 + bo);
                f16x8 bf2 = *(const f16x8*)(b2 + bo);
#pragma unroll
                for (int m = 0; m < 2; ++m) {
                    acc[m][j]  = __builtin_amdgcn_mfma_f32_16x16x32_f16(af1[m], bf1, acc[m][j],  0, 0, 0);
                    accc[m][j] = __builtin_amdgcn_mfma_f32_16x16x32_f16(af1[m], bf2, accc[m][j], 0, 0, 0);
                    accc[m][j] = __builtin_amdgcn_mfma_f32_16x16x32_f16(af2[m], bf1, accc[m][j], 0, 0, 0);
                }
            }
        }
    };

    // ---- prologue: FIFO=[A0:2, DMA0:4] -> split waits A0 (vmcnt(4));
    // then loadA(1); VMWAIT(2) drains DMA0, leaves A1; publish buf0.
    loadA(0);
    stageB(0, 0);
    SB0();
    splitWriteA(0);
    loadA(1);
    SB0(); VMWAIT(2); SB0();
    LGKM0();
    __builtin_amdgcn_s_barrier();

    // ITER(ch): stage ch+1 into buf[Q] (its reads finished before the PREVIOUS
    // barrier -> race-free), split A(ch+1) into buf[Q], compute ch from buf[P].
#define ITER(CH, P, Q, LOADNEXT, WN) do {                                   \
        stageB((CH) + 1, Q); SB0();                                         \
        splitWriteA(Q);                                                     \
        if (LOADNEXT) loadA((CH) + 2);                                      \
        mfmaStep(P);                                                        \
        SB0(); VMWAIT(WN); SB0();                                           \
        LGKM0();                                                            \
        __builtin_amdgcn_s_barrier();                                       \
    } while (0)

    for (int ch = 0; ch < NCH - 2; ch += 2) {
        ITER(ch,     0, 1, 1, 2);
        ITER(ch + 1, 1, 0, 1, 2);
    }
    ITER(NCH - 2, 0, 1, 0, 0);        // stages B(31)+A(31)->buf1; VMWAIT(0): last DMA
    mfmaStep(1);                      // ch = 31
    __syncthreads();                  // all LDS traffic done before epil overlay

#undef ITER

    // ---- epilogue: logits -> LDS; D layout: token=(2mg+m)*16+quad*4+r, expert=(2ng+j)*16+col
#pragma unroll
    for (int m = 0; m < 2; ++m)
#pragma unroll
        for (int j = 0; j < 2; ++j)
#pragma unroll
            for (int r = 0; r < 4; ++r)
                epil[((mg * 2 + m) * 16 + quad * 4 + r) * 132 + (ng * 2 + j) * 16 + col] =
                    acc[m][j][r] + accc[m][j][r] * INV_SPLIT_SCALE;
    __syncthreads();

    // ---- top-8 + renorm softmax: 8 tokens per wave (butterfly, verified) ----
    for (int i = 0; i < 8; ++i) {
        const int t = wv * 8 + i;
        float2 p = *(const float2*)(epil + t * 132 + 2 * lane);
        float v0 = p.x, v1 = p.y;
        const int i0 = 2 * lane, i1 = 2 * lane + 1;

        float topv[TOPK];
        int topi[TOPK];
#pragma unroll
        for (int s = 0; s < TOPK; ++s) {
            float mv = (v0 >= v1) ? v0 : v1;          // tie -> smaller index
            int   mi = (v0 >= v1) ? i0 : i1;
#pragma unroll
            for (int off = 32; off >= 1; off >>= 1) {
                float ov = __shfl_xor(mv, off);
                int   oi = __shfl_xor(mi, off);
                if (ov > mv || (ov == mv && oi < mi)) { mv = ov; mi = oi; }
            }
            topv[s] = mv; topi[s] = mi;
            if (i0 == mi) v0 = -INFINITY;
            if (i1 == mi) v1 = -INFINITY;
        }

        const float m = topv[0];
        float sum = 0.f;
#pragma unroll
        for (int s = 0; s < TOPK; ++s) sum += expf(topv[s] - m);
        const float inv = 1.f / sum;

        float myv = topv[0]; int myi = topi[0];
#pragma unroll
        for (int s = 1; s < TOPK; ++s)
            if (lane == s) { myv = topv[s]; myi = topi[s]; }

        if (lane < TOPK) {
            long tok = tok0 + t;
            out_idx[tok * TOPK + lane] = (float)myi;
            out_w[tok * TOPK + lane]   = expf(myv - m) * inv;
        }
    }
}

extern "C" void kernel_launch(void* const* d_in, const int* in_sizes, int n_in,
                              void* d_out, int out_size, void* d_ws, size_t ws_size,
                              hipStream_t stream) {
    const float* x = (const float*)d_in[0];   // [4,4096,2048] fp32
    const float* w = (const float*)d_in[1];   // [128,2048] fp32
    float* out = (float*)d_out;               // [T*8 idx][T*8 weights] flat fp32

    unsigned short* wp1 = (unsigned short*)d_ws;           // 512 KB packed hi
    unsigned short* wp2 = wp1 + (size_t)NEXP * HDIM;       // 512 KB packed lo

    pack_w<<<(64 * 8 * 64) / 256, 256, 0, stream>>>(w, wp1, wp2);
    moe_gate<<<T_TOKENS / TM, 512, 98304, stream>>>(x, wp1, wp2, out,
                                                    out + (size_t)T_TOKENS * TOPK);
}